// Round 17
// baseline (341.769 us; speedup 1.0000x reference)
//
#include <hip/hip_runtime.h>
#include <hip/hip_bf16.h>
#include <math.h>

// Problem dims (fixed by the reference)
#define B_  64
#define S_  512
#define D_  1024
#define E2_ 1024
#define WROW (D_ + E2_)   // 2048, row stride of w_weight
#define NTILES 4          // D_ / BNE (256-wide n-tiles)

typedef __attribute__((ext_vector_type(8))) short bf16x8;
typedef __attribute__((ext_vector_type(4))) float f32x4;

// round-to-nearest-even f32 -> bf16 (scalar, prep kernel)
__device__ __forceinline__ unsigned short f2bf(float f) {
    unsigned u = __float_as_uint(f);
    u = (u + 0x7FFFu + ((u >> 16) & 1u)) >> 16;
    return (unsigned short)u;
}

// branch-free tanh via v_exp_f32: tanh(x) = sign(x)*(e^{2|x|}-1)/(e^{2|x|}+1)
__device__ __forceinline__ float fast_tanh(float x) {
    float ax = fminf(fabsf(x), 16.0f);                       // tanh(16)==1.0f
    float t  = __builtin_amdgcn_exp2f(ax * 2.8853900817779268f); // e^{2ax}
    float r  = (t - 1.0f) * __builtin_amdgcn_rcpf(t + 1.0f);
    return copysignf(r, x);
}

// ---------------------------------------------------------------------------
// PREP: merged conv_we (blocks [0,1024)) + dec_proj (blocks [1024,2048)).
// ---------------------------------------------------------------------------
__global__ __launch_bounds__(256) void prep_kernel(
        const float* __restrict__ w,      // (D, 2048)
        const float* __restrict__ dec,    // (B, D)
        const float* __restrict__ bias,   // (D)
        unsigned short* __restrict__ web, // (D, E2) bf16
        float* __restrict__ t)            // (B, D)
{
    const int blk = blockIdx.x;
    const int tid = threadIdx.x;

    if (blk < D_) {
        // ---- conv_we: row k = blk ----
        const int k = blk;
        const int j = tid * 4;
        float4 a = *reinterpret_cast<const float4*>(w + (size_t)k * WROW + D_ + j);
        ushort4 o;
        o.x = f2bf(a.x); o.y = f2bf(a.y); o.z = f2bf(a.z); o.w = f2bf(a.w);
        *reinterpret_cast<ushort4*>(web + (size_t)k * E2_ + j) = o;
    } else {
        // ---- dec_proj: t[b][k] = dot(dec[b], Wd[k]) + bias[k] ----
        __shared__ float wrow[D_];
        __shared__ float red[256];
        const int k = blk - D_;
        const float* wr = w + (size_t)k * WROW;
        for (int i = tid; i < D_; i += 256) wrow[i] = wr[i];
        __syncthreads();

        const int b = tid >> 2;
        const int q = tid & 3;
        const float* dp = dec + b * D_ + q * 256;
        const float* wp = wrow + q * 256;
        float acc = 0.f;
        #pragma unroll 8
        for (int i = 0; i < 256; ++i) acc = fmaf(dp[i], wp[i], acc);
        red[tid] = acc;
        __syncthreads();
        if (q == 0) {
            float s = red[tid] + red[tid + 1] + red[tid + 2] + red[tid + 3];
            t[b * D_ + k] = s + bias[k];
        }
    }
}

// ---------------------------------------------------------------------------
// Kernel B: 256x256 tile, BK=64, 8 waves (2 wm x 4 wn), 512 threads.
// A: fused f32->bf16 (R11 path) in LDS (double-buffered, XOR-swizzled).
// B: NO LDS — fragments loaded DIRECTLY global->registers (each frag instr
// reads 16 rows x 64B = full cachelines; B is XCD-L2-resident under the
// m-locality swizzle). Cuts LDS traffic 256->160 KB/kt; compiler tracks all
// load->use waits (no manual vmcnt); only the A barrier + lgkmcnt(0) remain.
// bb registers: named cur/nxt arrays, unroll-by-2 swap (rule #20).
//   kt: loadB4(nxt,kk0) | SB | MFMA kk0 | SB | writeA(kt+1) issueA(kt+2) |
//       loadB4(nxt,kk1) | SB | MFMA kk1 | SB | lgkmcnt(0) | s_barrier
// LDS: phys r*128 + (kb^((r&7)<<4)). Grid 512 = 128 mblk x 4 ntile, XCD
// m-locality. Fused epilogue: tanh + v-dot + reduce -> att_part (B*S, 4).
// ---------------------------------------------------------------------------
#define BME 256
#define BNE 256
#define BKE 64
#define KT_ (E2_ / BKE)   // 16 K-tiles

__global__ __launch_bounds__(512) void energy_mfma_kernel(
        const float* __restrict__ encf,           // (B*S, E2) f32
        const unsigned short* __restrict__ web,   // (D, E2) bf16
        const float* __restrict__ t,              // (B, D)
        const float* __restrict__ v,              // (D)
        float* __restrict__ att_part)             // (B*S, NTILES)
{
    __shared__ __align__(16) unsigned short As[2][BME * BKE];  // 2 x 32 KB
    __shared__ float tv_s[BNE];
    __shared__ float vv_s[BNE];
    __shared__ float red[4][BME];

    // XCD m-locality swizzle: 512 blocks = 128 mblk x 4 ntile.
    const int g     = blockIdx.x;
    const int mblk  = (g & 7) + 8 * (g >> 5);
    const int ntile = (g >> 3) & 3;

    const int m0 = mblk * BME;
    const int n0 = ntile * BNE;
    const int b  = m0 >> 9;                 // 256-row tile never spans batches
    const int tid = threadIdx.x;
    const int w   = tid >> 6;               // wave 0..7
    const int l   = tid & 63;
    const int wm  = w >> 2;                 // wave row (0..1) -> 128 m-rows
    const int wn  = w & 3;                  // wave col (0..3) -> 64 n-cols

    if (tid < BNE) {
        tv_s[tid] = t[b * D_ + n0 + tid];
        vv_s[tid] = v[n0 + tid];
    }

    // --- A reg-staging geometry (f32 source, coalesced 16B/lane) ---
    const int arow0 = tid >> 4;              // 0..31; row&7 == arow0&7
    const int acolb = (tid & 15) * 8;        // byte col in bf16 LDS row
    const int aswz  = (arow0 & 7) << 4;
    const float* gAf = encf + (size_t)m0 * E2_;

    // --- A frag read offsets (LDS) ---
    const int rA = wm * 128 + (l & 15);
    const int kswz = (l & 7) << 4;
    const int khi  = (l >> 4) << 4;

    // --- B frag source (DIRECT global): frag (ni,kk) of tile kt at
    //     web[(n0 + wn*64 + ni*16 + (l&15)) * E2_ + kt*64 + kk*32 + (l>>4)*8]
    const unsigned short* gBf =
        web + (size_t)(n0 + wn * 64 + (l & 15)) * E2_ + (l >> 4) * 8;

    f32x4 acc[8][4] = {};
    float4 av[8];                            // tile-(kt+1) A data (32 VGPR)
    bf16x8 bbA[8], bbB[8];                   // B frags: cur / next tile

    auto issueA = [&](int kt) {
        const int k0 = kt * BKE;
        #pragma unroll
        for (int i = 0; i < 8; ++i) {
            const int row = i * 32 + arow0;
            av[i] = *reinterpret_cast<const float4*>(
                gAf + (size_t)row * E2_ + k0 + (tid & 15) * 4);
        }
    };
    auto writeA = [&](int bf) {
        #pragma unroll
        for (int i = 0; i < 8; ++i) {
            const int row = i * 32 + arow0;
            unsigned p0, p1;
            asm("v_cvt_pk_bf16_f32 %0, %1, %2"
                : "=v"(p0) : "v"(av[i].x), "v"(av[i].y));
            asm("v_cvt_pk_bf16_f32 %0, %1, %2"
                : "=v"(p1) : "v"(av[i].z), "v"(av[i].w));
            uint2 o; o.x = p0; o.y = p1;
            *reinterpret_cast<uint2*>(
                (char*)As[bf] + row * 128 + (acolb ^ aswz)) = o;
        }
    };

    #define LOADB4(dst, kt, kk)                                              \
        { _Pragma("unroll")                                                  \
          for (int ni = 0; ni < 4; ++ni)                                     \
              dst[(kk) * 4 + ni] = *reinterpret_cast<const bf16x8*>(         \
                  gBf + (size_t)(ni * 16) * E2_ + (kt) * BKE + (kk) * 32); }

    #define MFMA_HALF(cur, bb, kk)                                           \
        {   const int kb = ((kk) * 64 + khi) ^ kswz;                         \
            bf16x8 a[8];                                                     \
            _Pragma("unroll")                                                \
            for (int mi = 0; mi < 8; ++mi)                                   \
                a[mi] = *reinterpret_cast<const bf16x8*>(                    \
                    (const char*)As[cur] + (rA + mi * 16) * 128 + kb);       \
            __builtin_amdgcn_s_setprio(1);                                   \
            _Pragma("unroll")                                                \
            for (int mi = 0; mi < 8; ++mi)                                   \
                _Pragma("unroll")                                            \
                for (int ni = 0; ni < 4; ++ni)                               \
                    acc[mi][ni] = __builtin_amdgcn_mfma_f32_16x16x32_bf16(   \
                        a[mi], bb[(kk) * 4 + ni], acc[mi][ni], 0, 0, 0);     \
            __builtin_amdgcn_s_setprio(0);                                   \
        }

    // body for one kt; bbU = this tile's frags, bbF = next tile's (filled)
    #define KT_BODY(kt, cur, bbU, bbF)                                       \
        {   const int nxt = (cur) ^ 1;                                       \
            if ((kt) + 1 < KT_) LOADB4(bbF, (kt) + 1, 0);                    \
            __builtin_amdgcn_sched_barrier(0);                               \
            MFMA_HALF(cur, bbU, 0);                                          \
            __builtin_amdgcn_sched_barrier(0);                               \
            if ((kt) + 1 < KT_) writeA(nxt);                                 \
            if ((kt) + 2 < KT_) issueA((kt) + 2);                            \
            if ((kt) + 1 < KT_) LOADB4(bbF, (kt) + 1, 1);                    \
            __builtin_amdgcn_sched_barrier(0);                               \
            MFMA_HALF(cur, bbU, 1);                                          \
            __builtin_amdgcn_sched_barrier(0);                               \
            asm volatile("s_waitcnt lgkmcnt(0)" ::: "memory");               \
            __builtin_amdgcn_s_barrier();                                    \
            __builtin_amdgcn_sched_barrier(0);                               \
        }

    // prologue: A tile 0 staged; av <- tile 1; bbA <- tile 0 frags
    issueA(0);
    LOADB4(bbA, 0, 0);
    LOADB4(bbA, 0, 1);
    writeA(0);               // compiler waits exactly the av loads
    issueA(1);
    asm volatile("s_waitcnt lgkmcnt(0)" ::: "memory");
    __builtin_amdgcn_s_barrier();
    __builtin_amdgcn_sched_barrier(0);

    #pragma unroll 1
    for (int kt2 = 0; kt2 < KT_ / 2; ++kt2) {
        const int kt0 = kt2 * 2;
        KT_BODY(kt0,     0, bbA, bbB);
        KT_BODY(kt0 + 1, 1, bbB, bbA);
    }

    // --- epilogue: tanh + v-dot, reduce over n ---
    // D frag mapping: col = l&15, row = (l>>4)*4 + j  [m89-verified]
    #pragma unroll
    for (int mi = 0; mi < 8; ++mi) {
        float P[4] = {0.f, 0.f, 0.f, 0.f};
        #pragma unroll
        for (int ni = 0; ni < 4; ++ni) {
            const int nl = wn * 64 + ni * 16 + (l & 15);
            const float tvv = tv_s[nl];
            const float vvv = vv_s[nl];
            #pragma unroll
            for (int j = 0; j < 4; ++j) {
                float e = fast_tanh(acc[mi][ni][j] + tvv);
                P[j] = fmaf(e, vvv, P[j]);
            }
        }
        #pragma unroll
        for (int j = 0; j < 4; ++j) {
            float p = P[j];
            p += __shfl_xor(p, 1);
            p += __shfl_xor(p, 2);
            p += __shfl_xor(p, 4);
            p += __shfl_xor(p, 8);
            if ((l & 15) == 0)
                red[wn][wm * 128 + mi * 16 + (l >> 4) * 4 + j] = p;
        }
    }
    __syncthreads();
    if (tid < BME)
        att_part[(size_t)(m0 + tid) * NTILES + ntile] =
            (red[0][tid] + red[1][tid]) + (red[2][tid] + red[3][tid]);
}

// ---------------------------------------------------------------------------
// Kernel C: fused softmax + partial weighted sum, f32 enc (L3-resident).
// Grid (8 s-chunks, B), 256 threads (float4/lane covers E2).
// ---------------------------------------------------------------------------
__global__ __launch_bounds__(256) void attout_sm_kernel(
        const float* __restrict__ att_part,  // (B*S, NTILES=4)
        const int* __restrict__ mask,        // (B, S)
        const float* __restrict__ enc,       // (B, S, E2) f32
        float* __restrict__ out_part)        // (8, B, E2)
{
    __shared__ float wall[S_];
    __shared__ float red[256];
    const int b  = blockIdx.y;
    const int sc = blockIdx.x;            // 0..7
    const int tid = threadIdx.x;          // 0..255

    // ---- softmax over the full row (each thread owns s = tid + j*256) ----
    float x[2];
    bool mv[2];
    #pragma unroll
    for (int j = 0; j < 2; ++j) {
        const int s = tid + j * 256;
        float4 p = *reinterpret_cast<const float4*>(
            att_part + (size_t)(b * S_ + s) * NTILES);
        x[j] = (p.x + p.y) + (p.z + p.w);
        mv[j] = (mask[b * S_ + s] != 0);
        if (!mv[j]) x[j] = -INFINITY;
    }
    float m = fmaxf(x[0], x[1]);
    red[tid] = m;
    __syncthreads();
    for (int o = 128; o > 0; o >>= 1) {
        if (tid < o) red[tid] = fmaxf(red[tid], red[tid + o]);
        __syncthreads();
    }
    m = red[0];
    __syncthreads();
    float e0 = mv[0] ? expf(x[0] - m) : 0.f;
    float e1 = mv[1] ? expf(x[1] - m) : 0.f;
    red[tid] = e0 + e1;
    __syncthreads();
    for (int o = 128; o > 0; o >>= 1) {
        if (tid < o) red[tid] += red[tid + o];
        __syncthreads();
    }
    const float inv = 1.f / red[0];
    wall[tid] = e0 * inv;
    wall[tid + 256] = e1 * inv;
    __syncthreads();

    // ---- weighted sum over own 64-s chunk, float4 per lane ----
    const float* wsm = wall + sc * 64;
    const float4* ep = reinterpret_cast<const float4*>(
        enc + ((size_t)b * S_ + sc * 64) * E2_) + tid;
    float4 acc = {0.f, 0.f, 0.f, 0.f};
    #pragma unroll 8
    for (int s = 0; s < 64; ++s) {
        float4 e4 = ep[(size_t)s * (E2_ / 4)];
        const float ws = wsm[s];
        acc.x = fmaf(ws, e4.x, acc.x);
        acc.y = fmaf(ws, e4.y, acc.y);
        acc.z = fmaf(ws, e4.z, acc.z);
        acc.w = fmaf(ws, e4.w, acc.w);
    }
    reinterpret_cast<float4*>(out_part + ((size_t)sc * B_ + b) * E2_)[tid] = acc;
}

__global__ __launch_bounds__(256) void attout_reduce_kernel(
        const float* __restrict__ out_part,  // (8, B, E2)
        float* __restrict__ out)             // (B, E2)
{
    const int idx = blockIdx.x * 256 + threadIdx.x;   // float4 index
    const int n4 = (B_ * E2_) / 4;
    const float4* p = reinterpret_cast<const float4*>(out_part);
    float4 r = p[idx];
    #pragma unroll
    for (int c = 1; c < 8; ++c) {
        float4 q = p[idx + c * n4];
        r.x += q.x; r.y += q.y; r.z += q.z; r.w += q.w;
    }
    reinterpret_cast<float4*>(out)[idx] = r;
}

// ---------------------------------------------------------------------------
extern "C" void kernel_launch(void* const* d_in, const int* in_sizes, int n_in,
                              void* d_out, int out_size, void* d_ws, size_t ws_size,
                              hipStream_t stream) {
    const float* dec  = (const float*)d_in[0];   // (B, D)
    const float* enc  = (const float*)d_in[1];   // (B, S, E2)
    const int*   mask = (const int*)d_in[2];     // (B, S)
    const float* w    = (const float*)d_in[3];   // (D, D+E2)
    const float* bias = (const float*)d_in[4];   // (D)
    const float* v    = (const float*)d_in[5];   // (D)
    float* out = (float*)d_out;                  // (B, 1, E2)

    // workspace layout
    float* t_buf    = (float*)d_ws;                      // B*D          f32
    float* att_part = t_buf + B_ * D_;                   // B*S*NTILES   f32
    float* out_part = att_part + B_ * S_ * NTILES;       // 8*B*E2       f32
    unsigned short* web = (unsigned short*)(out_part + 8 * B_ * E2_); // D*E2

    prep_kernel<<<2 * D_, 256, 0, stream>>>(w, dec, bias, web, t_buf);
    energy_mfma_kernel<<<512, 512, 0, stream>>>(enc, web, t_buf, v, att_part);
    attout_sm_kernel<<<dim3(8, B_), 256, 0, stream>>>(att_part, mask,
                                                      enc, out_part);
    attout_reduce_kernel<<<(B_ * E2_ / 4) / 256, 256, 0, stream>>>(out_part, out);
}

// Round 18
// 136.517 us; speedup vs baseline: 2.5035x; 2.5035x over previous
//
#include <hip/hip_runtime.h>
#include <hip/hip_bf16.h>
#include <math.h>

// Problem dims (fixed by the reference)
#define B_  64
#define S_  512
#define D_  1024
#define E2_ 1024
#define WROW (D_ + E2_)   // 2048, row stride of w_weight
#define NTILES 4          // D_ / BNE (256-wide n-tiles)

typedef __attribute__((ext_vector_type(8))) short bf16x8;
typedef __attribute__((ext_vector_type(4))) float f32x4;
typedef __attribute__((ext_vector_type(8))) unsigned short u16x8;

// round-to-nearest-even f32 -> bf16 (scalar, prep kernel)
__device__ __forceinline__ unsigned short f2bf(float f) {
    unsigned u = __float_as_uint(f);
    u = (u + 0x7FFFu + ((u >> 16) & 1u)) >> 16;
    return (unsigned short)u;
}

__device__ __forceinline__ float bf2f(unsigned short u) {
    return __uint_as_float((unsigned)u << 16);
}

__device__ __forceinline__ void load_lds16(const void* g, void* l) {
    __builtin_amdgcn_global_load_lds(
        (__attribute__((address_space(1))) void*)(void*)g,
        (__attribute__((address_space(3))) void*)l,
        16, 0, 0);
}

// branch-free tanh via v_exp_f32: tanh(x) = sign(x)*(e^{2|x|}-1)/(e^{2|x|}+1)
__device__ __forceinline__ float fast_tanh(float x) {
    float ax = fminf(fabsf(x), 16.0f);                       // tanh(16)==1.0f
    float t  = __builtin_amdgcn_exp2f(ax * 2.8853900817779268f); // e^{2ax}
    float r  = (t - 1.0f) * __builtin_amdgcn_rcpf(t + 1.0f);
    return copysignf(r, x);
}

// ---------------------------------------------------------------------------
// PREP: merged conv_we (blocks [0,1024)) + dec_proj (blocks [1024,2048)).
// ---------------------------------------------------------------------------
__global__ __launch_bounds__(256) void prep_kernel(
        const float* __restrict__ w,      // (D, 2048)
        const float* __restrict__ dec,    // (B, D)
        const float* __restrict__ bias,   // (D)
        unsigned short* __restrict__ web, // (D, E2) bf16
        float* __restrict__ t)            // (B, D)
{
    const int blk = blockIdx.x;
    const int tid = threadIdx.x;

    if (blk < D_) {
        // ---- conv_we: row k = blk ----
        const int k = blk;
        const int j = tid * 4;
        float4 a = *reinterpret_cast<const float4*>(w + (size_t)k * WROW + D_ + j);
        ushort4 o;
        o.x = f2bf(a.x); o.y = f2bf(a.y); o.z = f2bf(a.z); o.w = f2bf(a.w);
        *reinterpret_cast<ushort4*>(web + (size_t)k * E2_ + j) = o;
    } else {
        // ---- dec_proj: t[b][k] = dot(dec[b], Wd[k]) + bias[k] ----
        __shared__ float wrow[D_];
        __shared__ float red[256];
        const int k = blk - D_;
        const float* wr = w + (size_t)k * WROW;
        for (int i = tid; i < D_; i += 256) wrow[i] = wr[i];
        __syncthreads();

        const int b = tid >> 2;
        const int q = tid & 3;
        const float* dp = dec + b * D_ + q * 256;
        const float* wp = wrow + q * 256;
        float acc = 0.f;
        #pragma unroll 8
        for (int i = 0; i < 256; ++i) acc = fmaf(dp[i], wp[i], acc);
        red[tid] = acc;
        __syncthreads();
        if (q == 0) {
            float s = red[tid] + red[tid + 1] + red[tid + 2] + red[tid + 3];
            t[b * D_ + k] = s + bias[k];
        }
    }
}

// ---------------------------------------------------------------------------
// Kernel B: 256x256 tile, BK=64, 8 waves (2 wm x 4 wn), 512 threads.
// FUSED f32->bf16 A conversion (R11-proven schedule) + distributed encb
// side-write (block ntile stores K-tiles [4*ntile,4*ntile+4) of its m-panel).
// Store-aware vmcnt ledger: global STORES increment vmcnt, so end-of-kt
// waits are vmcnt(16) on store-kts (A(kt+2)[8] + stores[8] in flight,
// retiring exactly B(kt+1)[4]).
//   kt: issueB(kt+1) | SB | MFMA kk0 | SB | writeA(kt+1)[+st] issueA(kt+2)
//       | SB | MFMA kk1 | SB | vmcnt(8 or 16) lgkmcnt(0) | s_barrier
// cvt via v_cvt_pk_bf16_f32 (RNE). LDS: phys r*128 + (kb^((r&7)<<4)).
// XCD m-locality swizzle: 4 n-tile blocks of one m-tile -> same XCD.
// Fused epilogue: tanh + v-dot + cross-wave reduce -> att_part (B*S, 4).
// ---------------------------------------------------------------------------
#define BME 256
#define BNE 256
#define BKE 64
#define KT_ (E2_ / BKE)   // 16 K-tiles

__global__ __launch_bounds__(512) void energy_mfma_kernel(
        const float* __restrict__ encf,           // (B*S, E2) f32
        const unsigned short* __restrict__ web,   // (D, E2) bf16
        const float* __restrict__ t,              // (B, D)
        const float* __restrict__ v,              // (D)
        float* __restrict__ att_part,             // (B*S, NTILES)
        unsigned short* __restrict__ encb)        // (B*S, E2) bf16 side-out
{
    __shared__ __align__(16) unsigned short As[2][BME * BKE];  // 2 x 32 KB
    __shared__ __align__(16) unsigned short Bs[2][BNE * BKE];  // 2 x 32 KB
    __shared__ float tv_s[BNE];
    __shared__ float vv_s[BNE];
    __shared__ float red[4][BME];

    // XCD m-locality swizzle: 512 blocks = 128 mblk x 4 ntile.
    const int g     = blockIdx.x;
    const int mblk  = (g & 7) + 8 * (g >> 5);
    const int ntile = (g >> 3) & 3;

    const int m0 = mblk * BME;
    const int n0 = ntile * BNE;
    const int b  = m0 >> 9;                 // 256-row tile never spans batches
    const int tid = threadIdx.x;
    const int w   = tid >> 6;               // wave 0..7
    const int l   = tid & 63;
    const int wm  = w >> 2;                 // wave row (0..1) -> 128 m-rows
    const int wn  = w & 3;                  // wave col (0..3) -> 64 n-cols

    if (tid < BNE) {
        tv_s[tid] = t[b * D_ + n0 + tid];
        vv_s[tid] = v[n0 + tid];
    }

    // --- A reg-staging geometry (f32 source, coalesced 16B/lane) ---
    const int arow0 = tid >> 4;              // 0..31; row&7 == arow0&7
    const int acolb = (tid & 15) * 8;        // byte col in bf16 LDS row
    const int aswz  = (arow0 & 7) << 4;
    const float* gAf = encf + (size_t)m0 * E2_;
    unsigned short* gOut = encb + (size_t)m0 * E2_;

    // --- B staging source address (inverse-swizzled global, gload_lds) ---
    const int lr8 = l >> 3;
    const int lk  = 8 * ((l & 7) ^ lr8);
    const unsigned short* gB = web + (size_t)n0 * E2_;

    // --- frag read offsets ---
    const int rA = wm * 128 + (l & 15);
    const int rB = wn * 64 + (l & 15);
    const int kswz = (l & 7) << 4;
    const int khi  = (l >> 4) << 4;

    f32x4 acc[8][4] = {};
    float4 av[8];                            // tile-(kt+1) A data (32 VGPR)

    auto issueA = [&](int kt) {
        const int k0 = kt * BKE;
        #pragma unroll
        for (int i = 0; i < 8; ++i) {
            const int row = i * 32 + arow0;
            av[i] = *reinterpret_cast<const float4*>(
                gAf + (size_t)row * E2_ + k0 + (tid & 15) * 4);
        }
    };
    auto writeA = [&](int bf, int kt) {
        const int k0 = kt * BKE;
        const bool st = ((kt >> 2) == ntile);   // distributed store quarter
        #pragma unroll
        for (int i = 0; i < 8; ++i) {
            const int row = i * 32 + arow0;
            unsigned p0, p1;
            asm("v_cvt_pk_bf16_f32 %0, %1, %2"
                : "=v"(p0) : "v"(av[i].x), "v"(av[i].y));
            asm("v_cvt_pk_bf16_f32 %0, %1, %2"
                : "=v"(p1) : "v"(av[i].z), "v"(av[i].w));
            uint2 o; o.x = p0; o.y = p1;
            *reinterpret_cast<uint2*>(
                (char*)As[bf] + row * 128 + (acolb ^ aswz)) = o;
            if (st)
                *reinterpret_cast<uint2*>(
                    gOut + (size_t)row * E2_ + k0 + (tid & 15) * 4) = o;
        }
    };
    auto issueB = [&](int bf, int kt) {
        const int k0 = kt * BKE;
        #pragma unroll
        for (int r = 0; r < 4; ++r) {
            const int c = r * 8 + w;              // chunk 0..31
            const int row = c * 8 + lr8;          // 0..255
            load_lds16(gB + (size_t)row * E2_ + k0 + lk,
                       (char*)Bs[bf] + c * 1024);
        }
    };

    // prologue: tile 0 staged; av <- tile 1
    issueA(0);
    issueB(0, 0);
    writeA(0, 0);            // auto vmcnt waits only the A loads
    issueA(1);
    // retire B(0): in flight = B0[4] + (ntile==0 ? st[8] : 0) + A1[8]
    if (ntile == 0) {
        asm volatile("s_waitcnt vmcnt(16) lgkmcnt(0)" ::: "memory");
    } else {
        asm volatile("s_waitcnt vmcnt(8) lgkmcnt(0)" ::: "memory");
    }
    __builtin_amdgcn_s_barrier();
    __builtin_amdgcn_sched_barrier(0);

    for (int kt = 0; kt < KT_; ++kt) {
        const int cur = kt & 1;
        const int nxt = cur ^ 1;
        const bool st_now = (((kt + 1) >> 2) == ntile);  // writeA(kt+1) stores?

        if (kt + 1 < KT_) issueB(nxt, kt + 1);
        __builtin_amdgcn_sched_barrier(0);

        {   // ---- MFMA kk0 ----
            const int kb = khi ^ kswz;
            bf16x8 a[8], bb[4];
            #pragma unroll
            for (int mi = 0; mi < 8; ++mi)
                a[mi] = *reinterpret_cast<const bf16x8*>(
                    (const char*)As[cur] + (rA + mi * 16) * 128 + kb);
            #pragma unroll
            for (int ni = 0; ni < 4; ++ni)
                bb[ni] = *reinterpret_cast<const bf16x8*>(
                    (const char*)Bs[cur] + (rB + ni * 16) * 128 + kb);
            __builtin_amdgcn_s_setprio(1);
            #pragma unroll
            for (int mi = 0; mi < 8; ++mi)
                #pragma unroll
                for (int ni = 0; ni < 4; ++ni)
                    acc[mi][ni] = __builtin_amdgcn_mfma_f32_16x16x32_bf16(
                        a[mi], bb[ni], acc[mi][ni], 0, 0, 0);
            __builtin_amdgcn_s_setprio(0);
        }
        __builtin_amdgcn_sched_barrier(0);

        if (kt + 1 < KT_) writeA(nxt, kt + 1);  // cvt_pk + ds_write (+store)
        if (kt + 2 < KT_) issueA(kt + 2);       // refill av, full tile ahead
        __builtin_amdgcn_sched_barrier(0);

        {   // ---- MFMA kk1 ----
            const int kb = (64 + khi) ^ kswz;
            bf16x8 a[8], bb[4];
            #pragma unroll
            for (int mi = 0; mi < 8; ++mi)
                a[mi] = *reinterpret_cast<const bf16x8*>(
                    (const char*)As[cur] + (rA + mi * 16) * 128 + kb);
            #pragma unroll
            for (int ni = 0; ni < 4; ++ni)
                bb[ni] = *reinterpret_cast<const bf16x8*>(
                    (const char*)Bs[cur] + (rB + ni * 16) * 128 + kb);
            __builtin_amdgcn_s_setprio(1);
            #pragma unroll
            for (int mi = 0; mi < 8; ++mi)
                #pragma unroll
                for (int ni = 0; ni < 4; ++ni)
                    acc[mi][ni] = __builtin_amdgcn_mfma_f32_16x16x32_bf16(
                        a[mi], bb[ni], acc[mi][ni], 0, 0, 0);
            __builtin_amdgcn_s_setprio(0);
        }
        __builtin_amdgcn_sched_barrier(0);

        // end-of-kt: retire B(kt+1). In flight after wait:
        //   A(kt+2)[8] + (st_now ? stores[8] : 0)
        if (kt + 2 < KT_) {
            if (st_now) {
                asm volatile("s_waitcnt vmcnt(16) lgkmcnt(0)" ::: "memory");
            } else {
                asm volatile("s_waitcnt vmcnt(8) lgkmcnt(0)" ::: "memory");
            }
        } else if (kt + 1 < KT_) {
            // kt=14: no A(16) issued; in flight = B(15)[4] + (st? stores[8])
            if (st_now) {
                asm volatile("s_waitcnt vmcnt(8) lgkmcnt(0)" ::: "memory");
            } else {
                asm volatile("s_waitcnt vmcnt(0) lgkmcnt(0)" ::: "memory");
            }
        }
        __builtin_amdgcn_s_barrier();
        __builtin_amdgcn_sched_barrier(0);
    }

    // --- epilogue: tanh + v-dot, reduce over n ---
    // D frag mapping: col = l&15, row = (l>>4)*4 + j  [m89-verified]
    #pragma unroll
    for (int mi = 0; mi < 8; ++mi) {
        float P[4] = {0.f, 0.f, 0.f, 0.f};
        #pragma unroll
        for (int ni = 0; ni < 4; ++ni) {
            const int nl = wn * 64 + ni * 16 + (l & 15);
            const float tvv = tv_s[nl];
            const float vvv = vv_s[nl];
            #pragma unroll
            for (int j = 0; j < 4; ++j) {
                float e = fast_tanh(acc[mi][ni][j] + tvv);
                P[j] = fmaf(e, vvv, P[j]);
            }
        }
        #pragma unroll
        for (int j = 0; j < 4; ++j) {
            float p = P[j];
            p += __shfl_xor(p, 1);
            p += __shfl_xor(p, 2);
            p += __shfl_xor(p, 4);
            p += __shfl_xor(p, 8);
            if ((l & 15) == 0)
                red[wn][wm * 128 + mi * 16 + (l >> 4) * 4 + j] = p;
        }
    }
    __syncthreads();
    if (tid < BME)
        att_part[(size_t)(m0 + tid) * NTILES + ntile] =
            (red[0][tid] + red[1][tid]) + (red[2][tid] + red[3][tid]);
}

// ---------------------------------------------------------------------------
// Kernel C: fused softmax + partial weighted sum (bf16 encb).
// ---------------------------------------------------------------------------
__global__ __launch_bounds__(128) void attout_sm_kernel(
        const float* __restrict__ att_part,       // (B*S, NTILES=4)
        const int* __restrict__ mask,             // (B, S)
        const unsigned short* __restrict__ encb,  // (B, S, E2) bf16
        float* __restrict__ out_part)             // (8, B, E2)
{
    __shared__ float wall[S_];
    __shared__ float red[128];
    const int b  = blockIdx.y;
    const int sc = blockIdx.x;            // 0..7
    const int tid = threadIdx.x;          // 0..127

    // ---- softmax over the full row (each thread owns s = tid + j*128) ----
    float x[4];
    bool mv[4];
    #pragma unroll
    for (int j = 0; j < 4; ++j) {
        const int s = tid + j * 128;
        float4 p = *reinterpret_cast<const float4*>(
            att_part + (size_t)(b * S_ + s) * NTILES);
        x[j] = (p.x + p.y) + (p.z + p.w);
        mv[j] = (mask[b * S_ + s] != 0);
        if (!mv[j]) x[j] = -INFINITY;
    }
    float m = fmaxf(fmaxf(x[0], x[1]), fmaxf(x[2], x[3]));
    red[tid] = m;
    __syncthreads();
    for (int o = 64; o > 0; o >>= 1) {
        if (tid < o) red[tid] = fmaxf(red[tid], red[tid + o]);
        __syncthreads();
    }
    m = red[0];
    __syncthreads();
    float e[4], esum = 0.f;
    #pragma unroll
    for (int j = 0; j < 4; ++j) {
        e[j] = mv[j] ? expf(x[j] - m) : 0.f;
        esum += e[j];
    }
    red[tid] = esum;
    __syncthreads();
    for (int o = 64; o > 0; o >>= 1) {
        if (tid < o) red[tid] += red[tid + o];
        __syncthreads();
    }
    const float inv = 1.f / red[0];
    #pragma unroll
    for (int j = 0; j < 4; ++j) wall[tid + j * 128] = e[j] * inv;
    __syncthreads();

    // ---- weighted sum over own 64-s chunk, e8 per lane ----
    const float* wsm = wall + sc * 64;
    const unsigned short* ep =
        encb + ((size_t)b * S_ + sc * 64) * E2_ + tid * 8;
    float acc[8] = {};
    #pragma unroll 4
    for (int s = 0; s < 64; ++s) {
        u16x8 e8 = *reinterpret_cast<const u16x8*>(ep + (size_t)s * E2_);
        const float ws = wsm[s];
        #pragma unroll
        for (int j = 0; j < 8; ++j)
            acc[j] = fmaf(ws, bf2f((unsigned short)e8[j]), acc[j]);
    }
    float* op = out_part + ((size_t)sc * B_ + b) * E2_ + tid * 8;
    #pragma unroll
    for (int j = 0; j < 8; ++j) op[j] = acc[j];
}

__global__ __launch_bounds__(256) void attout_reduce_kernel(
        const float* __restrict__ out_part,  // (8, B, E2)
        float* __restrict__ out)             // (B, E2)
{
    const int idx = blockIdx.x * 256 + threadIdx.x;   // float4 index
    const int n4 = (B_ * E2_) / 4;
    const float4* p = reinterpret_cast<const float4*>(out_part);
    float4 r = p[idx];
    #pragma unroll
    for (int c = 1; c < 8; ++c) {
        float4 q = p[idx + c * n4];
        r.x += q.x; r.y += q.y; r.z += q.z; r.w += q.w;
    }
    reinterpret_cast<float4*>(out)[idx] = r;
}

// ---------------------------------------------------------------------------
extern "C" void kernel_launch(void* const* d_in, const int* in_sizes, int n_in,
                              void* d_out, int out_size, void* d_ws, size_t ws_size,
                              hipStream_t stream) {
    const float* dec  = (const float*)d_in[0];   // (B, D)
    const float* enc  = (const float*)d_in[1];   // (B, S, E2)
    const int*   mask = (const int*)d_in[2];     // (B, S)
    const float* w    = (const float*)d_in[3];   // (D, D+E2)
    const float* bias = (const float*)d_in[4];   // (D)
    const float* v    = (const float*)d_in[5];   // (D)
    float* out = (float*)d_out;                  // (B, 1, E2)

    // workspace layout
    float* t_buf    = (float*)d_ws;                      // B*D          f32
    float* att_part = t_buf + B_ * D_;                   // B*S*NTILES   f32
    float* out_part = att_part + B_ * S_ * NTILES;       // 8*B*E2       f32
    unsigned short* web  = (unsigned short*)(out_part + 8 * B_ * E2_); // D*E2
    unsigned short* encb = web + (size_t)D_ * E2_;       // B*S*E2       bf16

    prep_kernel<<<2 * D_, 256, 0, stream>>>(w, dec, bias, web, t_buf);
    energy_mfma_kernel<<<512, 512, 0, stream>>>(enc, web, t_buf, v,
                                                att_part, encb);
    attout_sm_kernel<<<dim3(8, B_), 128, 0, stream>>>(att_part, mask,
                                                      encb, out_part);
    attout_reduce_kernel<<<(B_ * E2_ / 4) / 256, 256, 0, stream>>>(out_part, out);
}